// Round 18
// baseline (869.692 us; speedup 1.0000x reference)
//
#include <hip/hip_runtime.h>
#include <cstdint>

#define S_LEN 4096
#define D_MODEL 768
#define NHEAD 12
#define DHE 64
#define DFF_ 3072
#define NL 4
#define W1_ 128
#define NC_ 32
#define QKVN 2304

typedef __attribute__((ext_vector_type(8))) short v8s;
typedef __attribute__((ext_vector_type(4))) short v4s;
typedef __attribute__((ext_vector_type(4))) float v4f;

__device__ __forceinline__ short f2bf(float f) {
  union { float f; unsigned u; } x; x.f = f;
  unsigned r = x.u + 0x7fffu + ((x.u >> 16) & 1u);
  return (short)(r >> 16);
}

__device__ __forceinline__ float b2f(short s) {
  union { unsigned u; float f; } x; x.u = ((unsigned)(unsigned short)s) << 16;
  return x.f;
}

__device__ __forceinline__ void load_lds16(const short* g, short* l) {
  __builtin_amdgcn_global_load_lds((const __attribute__((address_space(1))) void*)g,
                                   (__attribute__((address_space(3))) void*)l, 16, 0, 0);
}

// ---------------- 128xNB GEMM, 512 threads (8 waves 2x4, wave-tile 64x(NB/4)) ----------------
// R7-proven loop order + R15 strength-reduced addressing (best verified: 848.5 us).
// R18: NB=64 variant at launch_bounds(512,6) -> 3 blocks/CU (was silently capped at 2
// by the 4-waves/EU bound; LDS 48KB x3 = 144KB fits, VGPR 56 < 85-cap).
// EPI 0: bf16+bias. EPI 2: gelu->bf16.
// WRV: also write V-range cols (>=1536) transposed into vt [B,H,DH,S].
template<int NB, int EPI, int WRV>
__global__ __launch_bounds__(512, NB == 64 ? 6 : 4)
void gemm128(const short* __restrict__ A, const short* __restrict__ Bt,
             const float* __restrict__ bias, void* __restrict__ outp,
             short* __restrict__ vtw, int M, int N, int K)
{
  constexpr int CF = NB / 64;          // B frags per kk per wave (2 or 1)
  constexpr int BI = NB / 64;          // B stage issue rounds (2 or 1)
  constexpr int SI = 2 + BI;           // stage issues per thread (4 or 3)
  constexpr int ABUF = 128 * 64;       // shorts per A buffer (16KB)
  constexpr int BBUF = NB * 64;        // shorts per B buffer
  __shared__ short sA[2 * ABUF];
  __shared__ short sB[2 * BBUF];
  const int tid = threadIdx.x;
  const int lane = tid & 63, wid = tid >> 6;
  const int g = lane >> 4, l16 = lane & 15;
  const int wr = wid >> 2, wc = wid & 3;     // 2 x 4 wave grid
  const int nt = K >> 6;                     // always even here (12 or 48)

  // XCD-bijective swizzle (all grids have nwg % 8 == 0); bn-fastest within XCD chunk.
  const int gx = gridDim.x;
  const int nwg = gx * gridDim.y;
  const int p = blockIdx.y * gx + blockIdx.x;
  const int q8 = nwg >> 3;
  const int lb = (p & 7) * q8 + (p >> 3);
  const int bn_ = lb % gx, bm_ = lb / gx;

  const short* Ab = A + (size_t)(bm_ * 128) * K;
  const short* Bb = Bt + (size_t)(bn_ * NB) * K;

  // ---- hoisted per-thread stage pointers (global src) and LDS dsts
  const short* gAp[2];
  short* lAp[2];
  const short* gBp[BI];
  short* lBp[BI];
#pragma unroll
  for (int i = 0; i < 2; ++i) {
    const int byte = i * 8192 + tid * 16;
    const int row = byte >> 7;
    const int lir = (byte & 127) ^ ((row & 7) << 4);
    gAp[i] = Ab + (size_t)row * K + (lir >> 1);
    lAp[i] = &sA[(i * 8192 + wid * 1024) >> 1];
  }
#pragma unroll
  for (int i = 0; i < BI; ++i) {
    const int byte = i * 8192 + tid * 16;
    const int row = byte >> 7;
    const int lir = (byte & 127) ^ ((row & 7) << 4);
    gBp[i] = Bb + (size_t)row * K + (lir >> 1);
    lBp[i] = &sB[(i * 8192 + wid * 1024) >> 1];
  }
  // stage(bufi): issue from running pointers, bump by one K-tile (64 shorts)
  auto stage = [&](int bufi) {
#pragma unroll
    for (int i = 0; i < 2; ++i) {
      load_lds16(gAp[i], lAp[i] + bufi * ABUF);
      gAp[i] += 64;
    }
#pragma unroll
    for (int i = 0; i < BI; ++i) {
      load_lds16(gBp[i], lBp[i] + bufi * BBUF);
      gBp[i] += 64;
    }
  };

  // ---- hoisted ds_read base pointers: addr = base[kk] + CUR*bufbytes + m*2048
  const int swz = (l16 & 7) << 4;
  const char* aB[2];
  const char* bB[2];
#pragma unroll
  for (int kk = 0; kk < 2; ++kk) {
    const int koff = ((g * 16) ^ swz) ^ (kk * 64);
    aB[kk] = (const char*)sA + (wr * 64 + l16) * 128 + koff;
    bB[kk] = (const char*)sB + (wc * (CF * 16) + l16) * 128 + koff;
  }

  v4f acc[4][CF] = {};

  stage(0);
  stage(1);
  asm volatile("s_waitcnt vmcnt(%0)" :: "i"(SI) : "memory");
  __builtin_amdgcn_s_barrier();

#define GITER(CUR, T)                                                          \
  {                                                                            \
    v8s fa[2][4], fb[2][CF];                                                   \
    _Pragma("unroll")                                                          \
    for (int kk = 0; kk < 2; ++kk) {                                           \
      _Pragma("unroll")                                                        \
      for (int m = 0; m < 4; ++m)                                              \
        fa[kk][m] = *(const v8s*)(aB[kk] + (CUR) * (2 * ABUF) + m * 2048);     \
      _Pragma("unroll")                                                        \
      for (int n = 0; n < CF; ++n)                                             \
        fb[kk][n] = *(const v8s*)(bB[kk] + (CUR) * (2 * BBUF) + n * 2048);     \
    }                                                                          \
    asm volatile("s_waitcnt lgkmcnt(0)" ::: "memory");                         \
    __builtin_amdgcn_sched_barrier(0);                                         \
    __builtin_amdgcn_s_barrier();                                              \
    if ((T) + 2 < nt) stage(CUR);                                              \
    __builtin_amdgcn_sched_barrier(0);                                         \
    __builtin_amdgcn_s_setprio(1);                                             \
    _Pragma("unroll")                                                          \
    for (int kk = 0; kk < 2; ++kk)                                             \
      _Pragma("unroll")                                                        \
      for (int m = 0; m < 4; ++m)                                              \
        _Pragma("unroll")                                                      \
        for (int n = 0; n < CF; ++n)                                           \
          acc[m][n] = __builtin_amdgcn_mfma_f32_16x16x32_bf16(fa[kk][m], fb[kk][n], acc[m][n], 0, 0, 0); \
    __builtin_amdgcn_s_setprio(0);                                             \
    __builtin_amdgcn_sched_barrier(0);                                         \
    if ((T) + 2 < nt) {                                                        \
      asm volatile("s_waitcnt vmcnt(%0)" :: "i"(SI) : "memory");               \
    } else if ((T) + 1 < nt) {                                                 \
      asm volatile("s_waitcnt vmcnt(0)" ::: "memory");                         \
    }                                                                          \
    if ((T) + 1 < nt) __builtin_amdgcn_s_barrier();                            \
  }

  for (int t = 0; t < nt; t += 2) {
    GITER(0, t);
    GITER(1, t + 1);
  }
#undef GITER

  // epilogue
  const int row0 = bm_ * 128 + wr * 64;
  const int col0 = bn_ * NB + wc * (CF * 16);
#pragma unroll
  for (int m = 0; m < 4; ++m)
#pragma unroll
    for (int n = 0; n < CF; ++n) {
      const int col = col0 + n * 16 + l16;
      const float bc = bias[col];
      short pk4[4];
#pragma unroll
      for (int r = 0; r < 4; ++r) {
        const int row = row0 + m * 16 + g * 4 + r;
        const float v = acc[m][n][r] + bc;
        short o;
        if (EPI == 2) {
          const float e = __expf(1.5957691216057308f * (v + 0.044715f * v * v * v));
          o = f2bf(v - v / (1.0f + e));
        } else {
          o = f2bf(v);
        }
        ((short*)outp)[(size_t)row * N + col] = o;
        pk4[r] = o;
      }
      if (WRV) {
        if (col0 >= 1536) {        // whole block is V-range
          const int cc = col - 1536;
          const int h = cc >> 6, d = cc & 63;
          const int rowm = row0 + m * 16 + g * 4;
          const int b = rowm >> 12, s = rowm & (S_LEN - 1);
          v4s pk = { pk4[0], pk4[1], pk4[2], pk4[3] };
          *(v4s*)&vtw[(((size_t)b * NHEAD + h) * DHE + d) * S_LEN + s] = pk;
        }
      }
    }
}

// ---------------- batched 768x768 weight transpose: z -> (matrix m = z>>2, layer l = z&3) ----
__global__ __launch_bounds__(256)
void qkvo_trans(const float* __restrict__ Wq, const float* __restrict__ Wk,
                const float* __restrict__ Wv, const float* __restrict__ Wo,
                short* __restrict__ wqkvt, short* __restrict__ wot)
{
  __shared__ float t[32][33];
  const int n0 = blockIdx.x * 32, k0 = blockIdx.y * 32;
  const int l = blockIdx.z & 3, m = blockIdx.z >> 2;
  const size_t DD = (size_t)D_MODEL * D_MODEL;
  const size_t QL = (size_t)QKVN * D_MODEL;
  const float* src = (m == 0 ? Wq : m == 1 ? Wk : m == 2 ? Wv : Wo) + (size_t)l * DD;
  short* dst = (m < 3) ? (wqkvt + (size_t)l * QL + (size_t)m * D_MODEL * D_MODEL)
                       : (wot + (size_t)l * DD);
  const float scale = (m == 0) ? 0.125f : 1.0f;
  const int tx = threadIdx.x, ty = threadIdx.y;   // (32,8)
#pragma unroll
  for (int i = 0; i < 4; ++i)
    t[ty + 8*i][tx] = src[(size_t)(k0 + ty + 8*i) * D_MODEL + n0 + tx];
  __syncthreads();
#pragma unroll
  for (int i = 0; i < 4; ++i)
    dst[(size_t)(n0 + ty + 8*i) * D_MODEL + k0 + tx] = f2bf(t[tx][ty + 8*i] * scale);
}

// ---------------- weight transpose f32[K,N] -> bf16[N,K] (Wi / Wf) ----------------
__global__ __launch_bounds__(256)
void transpose_w(const float* __restrict__ in, short* __restrict__ out, int K, int N,
                 size_t in_ls, size_t out_ls, float scale)
{
  __shared__ float t[32][33];
  const int n0 = blockIdx.x * 32, k0 = blockIdx.y * 32;
  const float* src = in + (size_t)blockIdx.z * in_ls;
  short* dst = out + (size_t)blockIdx.z * out_ls;
  const int tx = threadIdx.x, ty = threadIdx.y;   // (32,8)
#pragma unroll
  for (int i = 0; i < 4; ++i)
    t[ty + 8*i][tx] = src[(size_t)(k0 + ty + 8*i) * N + n0 + tx];
  __syncthreads();
#pragma unroll
  for (int i = 0; i < 4; ++i)
    dst[(size_t)(n0 + ty + 8*i) * K + k0 + tx] = f2bf(t[tx][ty + 8*i] * scale);
}

__global__ void prep_bias(const float* __restrict__ bq, const float* __restrict__ bk,
                          const float* __restrict__ bv, float* __restrict__ out)
{
  const int l = blockIdx.x, p = blockIdx.y, c = threadIdx.x;
  const float* s = p == 0 ? bq : (p == 1 ? bk : bv);
  out[(l * 3 + p) * 768 + c] = s[l * 768 + c] * (p == 0 ? 0.125f : 1.0f);
}

// ---------------- LayerNorm, bf16 residual stream (R10-proven precision path) ----------------
template<int MODE, int FINAL>
__global__ __launch_bounds__(256)
void ln_kernel(const void* __restrict__ in0, const void* __restrict__ in1,
               const float* __restrict__ in2,
               const float* __restrict__ gamma, const float* __restrict__ beta,
               float* __restrict__ outf, short* __restrict__ outb)
{
  __shared__ float red[8];
  const int row = blockIdx.x;
  const int tid = threadIdx.x;
  const int wave = tid >> 6, lane = tid & 63;
  float v[3];
#pragma unroll
  for (int i = 0; i < 3; ++i) {
    const int c = tid + i * 256;
    const size_t idx = (size_t)row * D_MODEL + c;
    if (MODE == 0) {
      const int s = row & (S_LEN - 1);
      v[i] = ((const float*)in0)[idx] + ((const float*)in1)[(size_t)(2 + s) * D_MODEL + c] + in2[c];
    } else {
      v[i] = b2f(((const short*)in0)[idx]) + b2f(((const short*)in1)[idx]);
    }
  }
  float sum = v[0] + v[1] + v[2];
#pragma unroll
  for (int m = 1; m < 64; m <<= 1) sum += __shfl_xor(sum, m, 64);
  if (lane == 0) red[wave] = sum;
  __syncthreads();
  const float mean = (red[0] + red[1] + red[2] + red[3]) * (1.0f / 768.0f);
  float sq = 0.f;
#pragma unroll
  for (int i = 0; i < 3; ++i) { float d = v[i] - mean; sq += d * d; }
#pragma unroll
  for (int m = 1; m < 64; m <<= 1) sq += __shfl_xor(sq, m, 64);
  if (lane == 0) red[4 + wave] = sq;
  __syncthreads();
  const float var = (red[4] + red[5] + red[6] + red[7]) * (1.0f / 768.0f);
  const float rstd = 1.0f / sqrtf(var + 1e-12f);
#pragma unroll
  for (int i = 0; i < 3; ++i) {
    const int c = tid + i * 256;
    const size_t idx = (size_t)row * D_MODEL + c;
    const float o = (v[i] - mean) * rstd * gamma[c] + beta[c];
    if (FINAL) outf[idx] = o;
    outb[idx] = f2bf(o);
  }
}

// ---------------- fused attention v5 (R14-proven): V fetch hides under QK^T ----------------
__global__ __launch_bounds__(256, 2)
void att_fused(const short* __restrict__ qkv, const short* __restrict__ vt,
               const int* __restrict__ lengths, short* __restrict__ ctx)
{
  __shared__ __align__(16) short KP[320 * 64];   // K-window; later P [64][640B]
  __shared__ __align__(16) short Vl[64 * 320];   // Vt-window [64][640B]
  const int p = blockIdx.x;
  const int lb = (p & 7) * 192 + (p >> 3);       // XCD-contiguous: same (b,h) per XCD
  const int hq = lb & 1, c = (lb >> 1) & 31, bh = lb >> 6;
  const int b = bh / 12, h = bh - b * 12;
  const int len = lengths[b];
  const int tid = threadIdx.x;
  const int wave = tid >> 6, lane = tid & 63;
  const int g = lane >> 4, l16 = lane & 15;
  const int j0h = c * W1_ + hq * 64 - W1_;       // global j of window index 0

  // ---- stage K window  [10 issues]
  {
    const int row0 = tid >> 3;
    const int o = (tid & 7) * 16;
    const char* kcol = (const char*)qkv + (size_t)b * S_LEN * 4608 + 1536 + h * 128;
#pragma unroll
    for (int i = 0; i < 10; ++i) {
      const int r_ = i * 32 + row0;
      const int op = o ^ ((r_ & 7) << 4);
      int jg = j0h + r_;
      jg = jg < 0 ? 0 : (jg > S_LEN - 1 ? S_LEN - 1 : jg);
      load_lds16((const short*)(kcol + (size_t)jg * 4608 + op),
                 (short*)((char*)KP + i * 4096 + wave * 1024));
    }
  }
  __builtin_amdgcn_sched_barrier(0);
  // ---- Q fragments  [2 loads]
  const int qrow = c * W1_ + hq * 64 + wave * 16 + l16;
  const short* qp = qkv + (size_t)(b * S_LEN + qrow) * QKVN + h * DHE;
  const v8s a0 = *(const v8s*)(qp + g * 8);
  const v8s a1 = *(const v8s*)(qp + 32 + g * 8);
  __builtin_amdgcn_sched_barrier(0);
  // ---- stage Vt window  [10 issues, in flight through QK^T]
  {
    const char* vrow = (const char*)vt + ((size_t)(b * NHEAD + h) * DHE) * (S_LEN * 2);
#pragma unroll
    for (int r = 0; r < 10; ++r) {
      const int off = r * 4096 + tid * 16;
      const int rw = (int)(((unsigned)off * 6554u) >> 22);   // off / 640
      const int o = off - rw * 640;
      int jb = j0h * 2 + (o ^ ((rw & 7) << 4));
      jb = jb < 0 ? 0 : (jb > S_LEN * 2 - 16 ? S_LEN * 2 - 16 : jb);
      load_lds16((const short*)(vrow + (size_t)rw * (S_LEN * 2) + jb),
                 (short*)((char*)Vl + r * 4096 + wave * 1024));
    }
  }
  __builtin_amdgcn_sched_barrier(0);
  asm volatile("s_waitcnt vmcnt(10)" ::: "memory");   // K+Q done; V in flight
  __builtin_amdgcn_sched_barrier(0);
  __builtin_amdgcn_s_barrier();

  // ---- swapped QK^T
  v4f s[20];
  const int kswz = (l16 & 7) << 4;
#pragma unroll
  for (int nt = 0; nt < 20; ++nt) {
    const char* krow = (const char*)KP + (nt * 16 + l16) * 128;
    const v8s k0 = *(const v8s*)(krow + ((g * 16) ^ kswz));
    const v8s k1 = *(const v8s*)(krow + ((64 + g * 16) ^ kswz));
    v4f t = {0.f, 0.f, 0.f, 0.f};
    t = __builtin_amdgcn_mfma_f32_16x16x32_bf16(k0, a0, t, 0, 0, 0);
    t = __builtin_amdgcn_mfma_f32_16x16x32_bf16(k1, a1, t, 0, 0, 0);
    s[nt] = t;
  }

  // ---- mask + softmax
  const int qloc = wave * 16 + l16;
  float m = -3.0e38f;
#pragma unroll
  for (int nt = 0; nt < 20; ++nt)
#pragma unroll
    for (int r = 0; r < 4; ++r) {
      const int j = nt * 16 + g * 4 + r;
      const int jg = j0h + j;
      const bool ok = (j >= qloc) & (j <= qloc + 2 * W1_) & (jg >= 0) & (jg < len);
      const float v = ok ? s[nt][r] : -1e9f;
      s[nt][r] = v;
      m = fmaxf(m, v);
    }
  m = fmaxf(m, __shfl_xor(m, 16, 64));
  m = fmaxf(m, __shfl_xor(m, 32, 64));
  float su = 0.f;
#pragma unroll
  for (int nt = 0; nt < 20; ++nt)
#pragma unroll
    for (int r = 0; r < 4; ++r) {
      const float e = __expf(s[nt][r] - m);
      s[nt][r] = e;
      su += e;
    }
  su += __shfl_xor(su, 16, 64);
  su += __shfl_xor(su, 32, 64);
  const float f = (qrow < len) ? 1.0f / su : 0.0f;

  // ---- drain V, barrier, overwrite K with P
  asm volatile("s_waitcnt vmcnt(0)" ::: "memory");
  __builtin_amdgcn_sched_barrier(0);
  __builtin_amdgcn_s_barrier();
  const int pswz = (qloc & 7) << 4;
  char* prow = (char*)KP + qloc * 640;
#pragma unroll
  for (int nt = 0; nt < 20; ++nt) {
    v4s pk;
#pragma unroll
    for (int r = 0; r < 4; ++r) pk[r] = f2bf(s[nt][r] * f);
    *(v4s*)(prow + ((nt * 32 + g * 8) ^ pswz)) = pk;
  }
  asm volatile("s_waitcnt lgkmcnt(0)" ::: "memory");
  __builtin_amdgcn_sched_barrier(0);

  // ---- PV from LDS
  v4f acc[4] = {};
#pragma unroll
  for (int kc = 0; kc < 10; ++kc) {
    const v8s fa = *(const v8s*)(prow + ((kc * 64 + g * 16) ^ pswz));
#pragma unroll
    for (int dt = 0; dt < 4; ++dt) {
      const int vr = dt * 16 + l16;
      const v8s fb = *(const v8s*)((char*)Vl + vr * 640 + ((kc * 64 + g * 16) ^ ((vr & 7) << 4)));
      acc[dt] = __builtin_amdgcn_mfma_f32_16x16x32_bf16(fa, fb, acc[dt], 0, 0, 0);
    }
  }
  const int srow0 = c * W1_ + hq * 64 + wave * 16;
#pragma unroll
  for (int dt = 0; dt < 4; ++dt)
#pragma unroll
    for (int r = 0; r < 4; ++r)
      ctx[(size_t)(b * S_LEN + srow0 + g * 4 + r) * D_MODEL + h * DHE + dt * 16 + l16] = f2bf(acc[dt][r]);
}

extern "C" void kernel_launch(void* const* d_in, const int* in_sizes, int n_in,
                              void* d_out, int out_size, void* d_ws, size_t ws_size,
                              hipStream_t stream) {
  (void)in_sizes; (void)n_in; (void)out_size; (void)ws_size;
  const float* inputs  = (const float*)d_in[0];
  const int*   lengths = (const int*)d_in[1];
  const float* pos_emb = (const float*)d_in[2];
  const float* tok_emb = (const float*)d_in[3];
  const float* ln_emb_g = (const float*)d_in[4];
  const float* ln_emb_b = (const float*)d_in[5];
  const float* Wq = (const float*)d_in[6];
  const float* bq = (const float*)d_in[7];
  const float* Wk = (const float*)d_in[8];
  const float* bk = (const float*)d_in[9];
  const float* Wv = (const float*)d_in[10];
  const float* bv = (const float*)d_in[11];
  const float* Wo = (const float*)d_in[12];
  const float* bo = (const float*)d_in[13];
  const float* ln1_g = (const float*)d_in[14];
  const float* ln1_b = (const float*)d_in[15];
  const float* Wi = (const float*)d_in[16];
  const float* bi = (const float*)d_in[17];
  const float* Wf = (const float*)d_in[18];
  const float* bf2 = (const float*)d_in[19];
  const float* ln2_g = (const float*)d_in[20];
  const float* ln2_b = (const float*)d_in[21];

  const size_t MTOK = (size_t)2 * S_LEN;     // 8192
  const size_t DD  = (size_t)D_MODEL * D_MODEL;
  const size_t DDF = (size_t)D_MODEL * DFF_;

  char* ws = (char*)d_ws;
  size_t off = 0;
  auto alloc = [&](size_t bytes) { void* p = ws + off; off += (bytes + 255) & ~(size_t)255; return p; };

  short* xb    = (short*)alloc(MTOK * D_MODEL * 2);
  short* qkv   = (short*)alloc(MTOK * QKVN * 2);
  short* vtb   = (short*)alloc(MTOK * D_MODEL * 2);
  short* yb    = (short*)alloc(MTOK * D_MODEL * 2);
  short* ctxb  = (short*)alloc(MTOK * D_MODEL * 2);
  short* hb    = (short*)alloc(MTOK * DFF_ * 2);
  short* wqkvt = (short*)alloc((size_t)NL * QKVN * D_MODEL * 2);
  short* wot   = (short*)alloc((size_t)NL * DD * 2);
  short* wit   = (short*)alloc((size_t)NL * DDF * 2);
  short* wft   = (short*)alloc((size_t)NL * DDF * 2);
  float* bqkv  = (float*)alloc((size_t)NL * QKVN * 4);
  float* x = (float*)d_out;

  const dim3 tb(32, 8);
  const size_t QL = (size_t)QKVN * D_MODEL;
  qkvo_trans<<<dim3(24, 24, 16), tb, 0, stream>>>(Wq, Wk, Wv, Wo, wqkvt, wot);
  transpose_w<<<dim3(96, 24, NL), tb, 0, stream>>>(Wi, wit, D_MODEL, DFF_, DDF, DDF, 1.0f);
  transpose_w<<<dim3(24, 96, NL), tb, 0, stream>>>(Wf, wft, DFF_, D_MODEL, DDF, DDF, 1.0f);
  prep_bias<<<dim3(NL, 3), 768, 0, stream>>>(bq, bk, bv, bqkv);

  ln_kernel<0, 0><<<MTOK, 256, 0, stream>>>(inputs, pos_emb, tok_emb, ln_emb_g, ln_emb_b, x, xb);

  for (int l = 0; l < NL; ++l) {
    gemm128<128, 0, 1><<<dim3(18, 64), 512, 0, stream>>>(xb, wqkvt + (size_t)l * QL, bqkv + (size_t)l * QKVN,
                                                         qkv, vtb, (int)MTOK, QKVN, D_MODEL);
    att_fused<<<dim3(1536), 256, 0, stream>>>(qkv, vtb, lengths, ctxb);
    gemm128<64, 0, 0><<<dim3(12, 64), 512, 0, stream>>>(ctxb, wot + (size_t)l * DD, bo + l * D_MODEL,
                                                        yb, nullptr, (int)MTOK, D_MODEL, D_MODEL);
    ln_kernel<1, 0><<<MTOK, 256, 0, stream>>>(xb, yb, nullptr, ln1_g + l * D_MODEL, ln1_b + l * D_MODEL, x, xb);
    gemm128<128, 2, 0><<<dim3(24, 64), 512, 0, stream>>>(xb, wit + (size_t)l * DDF, bi + l * DFF_,
                                                         hb, nullptr, (int)MTOK, DFF_, D_MODEL);
    gemm128<64, 0, 0><<<dim3(12, 64), 512, 0, stream>>>(hb, wft + (size_t)l * DDF, bf2 + l * D_MODEL,
                                                        yb, nullptr, (int)MTOK, D_MODEL, DFF_);
    if (l < NL - 1)
      ln_kernel<1, 0><<<MTOK, 256, 0, stream>>>(xb, yb, nullptr, ln2_g + l * D_MODEL, ln2_b + l * D_MODEL, x, xb);
    else
      ln_kernel<1, 1><<<MTOK, 256, 0, stream>>>(xb, yb, nullptr, ln2_g + l * D_MODEL, ln2_b + l * D_MODEL, x, xb);
  }
}

// Round 19
// 847.687 us; speedup vs baseline: 1.0260x; 1.0260x over previous
//
#include <hip/hip_runtime.h>
#include <cstdint>

#define S_LEN 4096
#define D_MODEL 768
#define NHEAD 12
#define DHE 64
#define DFF_ 3072
#define NL 4
#define W1_ 128
#define NC_ 32
#define QKVN 2304

typedef __attribute__((ext_vector_type(8))) short v8s;
typedef __attribute__((ext_vector_type(4))) short v4s;
typedef __attribute__((ext_vector_type(4))) float v4f;

__device__ __forceinline__ short f2bf(float f) {
  union { float f; unsigned u; } x; x.f = f;
  unsigned r = x.u + 0x7fffu + ((x.u >> 16) & 1u);
  return (short)(r >> 16);
}

__device__ __forceinline__ float b2f(short s) {
  union { unsigned u; float f; } x; x.u = ((unsigned)(unsigned short)s) << 16;
  return x.f;
}

__device__ __forceinline__ void load_lds16(const short* g, short* l) {
  __builtin_amdgcn_global_load_lds((const __attribute__((address_space(1))) void*)g,
                                   (__attribute__((address_space(3))) void*)l, 16, 0, 0);
}

// ---------------- 128xNB GEMM, 512 threads (8 waves 2x4, wave-tile 64x(NB/4)) ----------------
// Terminal config (R15/R17-verified 848.5/850.8 us): R7 loop order, R15 addressing,
// both variants at 4 waves/EU (R18's 6-waves/EU on NB=64 regressed: pipe contention).
// EPI 0: bf16+bias. EPI 2: gelu->bf16.
// WRV: also write V-range cols (>=1536) transposed into vt [B,H,DH,S].
template<int NB, int EPI, int WRV>
__global__ __launch_bounds__(512, 4)
void gemm128(const short* __restrict__ A, const short* __restrict__ Bt,
             const float* __restrict__ bias, void* __restrict__ outp,
             short* __restrict__ vtw, int M, int N, int K)
{
  constexpr int CF = NB / 64;          // B frags per kk per wave (2 or 1)
  constexpr int BI = NB / 64;          // B stage issue rounds (2 or 1)
  constexpr int SI = 2 + BI;           // stage issues per thread (4 or 3)
  constexpr int ABUF = 128 * 64;       // shorts per A buffer (16KB)
  constexpr int BBUF = NB * 64;        // shorts per B buffer
  __shared__ short sA[2 * ABUF];
  __shared__ short sB[2 * BBUF];
  const int tid = threadIdx.x;
  const int lane = tid & 63, wid = tid >> 6;
  const int g = lane >> 4, l16 = lane & 15;
  const int wr = wid >> 2, wc = wid & 3;     // 2 x 4 wave grid
  const int nt = K >> 6;                     // always even here (12 or 48)

  // XCD-bijective swizzle (all grids have nwg % 8 == 0); bn-fastest within XCD chunk.
  const int gx = gridDim.x;
  const int nwg = gx * gridDim.y;
  const int p = blockIdx.y * gx + blockIdx.x;
  const int q8 = nwg >> 3;
  const int lb = (p & 7) * q8 + (p >> 3);
  const int bn_ = lb % gx, bm_ = lb / gx;

  const short* Ab = A + (size_t)(bm_ * 128) * K;
  const short* Bb = Bt + (size_t)(bn_ * NB) * K;

  // ---- hoisted per-thread stage pointers (global src) and LDS dsts
  const short* gAp[2];
  short* lAp[2];
  const short* gBp[BI];
  short* lBp[BI];
#pragma unroll
  for (int i = 0; i < 2; ++i) {
    const int byte = i * 8192 + tid * 16;
    const int row = byte >> 7;
    const int lir = (byte & 127) ^ ((row & 7) << 4);
    gAp[i] = Ab + (size_t)row * K + (lir >> 1);
    lAp[i] = &sA[(i * 8192 + wid * 1024) >> 1];
  }
#pragma unroll
  for (int i = 0; i < BI; ++i) {
    const int byte = i * 8192 + tid * 16;
    const int row = byte >> 7;
    const int lir = (byte & 127) ^ ((row & 7) << 4);
    gBp[i] = Bb + (size_t)row * K + (lir >> 1);
    lBp[i] = &sB[(i * 8192 + wid * 1024) >> 1];
  }
  // stage(bufi): issue from running pointers, bump by one K-tile (64 shorts)
  auto stage = [&](int bufi) {
#pragma unroll
    for (int i = 0; i < 2; ++i) {
      load_lds16(gAp[i], lAp[i] + bufi * ABUF);
      gAp[i] += 64;
    }
#pragma unroll
    for (int i = 0; i < BI; ++i) {
      load_lds16(gBp[i], lBp[i] + bufi * BBUF);
      gBp[i] += 64;
    }
  };

  // ---- hoisted ds_read base pointers: addr = base[kk] + CUR*bufbytes + m*2048
  const int swz = (l16 & 7) << 4;
  const char* aB[2];
  const char* bB[2];
#pragma unroll
  for (int kk = 0; kk < 2; ++kk) {
    const int koff = ((g * 16) ^ swz) ^ (kk * 64);
    aB[kk] = (const char*)sA + (wr * 64 + l16) * 128 + koff;
    bB[kk] = (const char*)sB + (wc * (CF * 16) + l16) * 128 + koff;
  }

  v4f acc[4][CF] = {};

  stage(0);
  stage(1);
  asm volatile("s_waitcnt vmcnt(%0)" :: "i"(SI) : "memory");
  __builtin_amdgcn_s_barrier();

#define GITER(CUR, T)                                                          \
  {                                                                            \
    v8s fa[2][4], fb[2][CF];                                                   \
    _Pragma("unroll")                                                          \
    for (int kk = 0; kk < 2; ++kk) {                                           \
      _Pragma("unroll")                                                        \
      for (int m = 0; m < 4; ++m)                                              \
        fa[kk][m] = *(const v8s*)(aB[kk] + (CUR) * (2 * ABUF) + m * 2048);     \
      _Pragma("unroll")                                                        \
      for (int n = 0; n < CF; ++n)                                             \
        fb[kk][n] = *(const v8s*)(bB[kk] + (CUR) * (2 * BBUF) + n * 2048);     \
    }                                                                          \
    asm volatile("s_waitcnt lgkmcnt(0)" ::: "memory");                         \
    __builtin_amdgcn_sched_barrier(0);                                         \
    __builtin_amdgcn_s_barrier();                                              \
    if ((T) + 2 < nt) stage(CUR);                                              \
    __builtin_amdgcn_sched_barrier(0);                                         \
    __builtin_amdgcn_s_setprio(1);                                             \
    _Pragma("unroll")                                                          \
    for (int kk = 0; kk < 2; ++kk)                                             \
      _Pragma("unroll")                                                        \
      for (int m = 0; m < 4; ++m)                                              \
        _Pragma("unroll")                                                      \
        for (int n = 0; n < CF; ++n)                                           \
          acc[m][n] = __builtin_amdgcn_mfma_f32_16x16x32_bf16(fa[kk][m], fb[kk][n], acc[m][n], 0, 0, 0); \
    __builtin_amdgcn_s_setprio(0);                                             \
    __builtin_amdgcn_sched_barrier(0);                                         \
    if ((T) + 2 < nt) {                                                        \
      asm volatile("s_waitcnt vmcnt(%0)" :: "i"(SI) : "memory");               \
    } else if ((T) + 1 < nt) {                                                 \
      asm volatile("s_waitcnt vmcnt(0)" ::: "memory");                         \
    }                                                                          \
    if ((T) + 1 < nt) __builtin_amdgcn_s_barrier();                            \
  }

  for (int t = 0; t < nt; t += 2) {
    GITER(0, t);
    GITER(1, t + 1);
  }
#undef GITER

  // epilogue
  const int row0 = bm_ * 128 + wr * 64;
  const int col0 = bn_ * NB + wc * (CF * 16);
#pragma unroll
  for (int m = 0; m < 4; ++m)
#pragma unroll
    for (int n = 0; n < CF; ++n) {
      const int col = col0 + n * 16 + l16;
      const float bc = bias[col];
      short pk4[4];
#pragma unroll
      for (int r = 0; r < 4; ++r) {
        const int row = row0 + m * 16 + g * 4 + r;
        const float v = acc[m][n][r] + bc;
        short o;
        if (EPI == 2) {
          const float e = __expf(1.5957691216057308f * (v + 0.044715f * v * v * v));
          o = f2bf(v - v / (1.0f + e));
        } else {
          o = f2bf(v);
        }
        ((short*)outp)[(size_t)row * N + col] = o;
        pk4[r] = o;
      }
      if (WRV) {
        if (col0 >= 1536) {        // whole block is V-range
          const int cc = col - 1536;
          const int h = cc >> 6, d = cc & 63;
          const int rowm = row0 + m * 16 + g * 4;
          const int b = rowm >> 12, s = rowm & (S_LEN - 1);
          v4s pk = { pk4[0], pk4[1], pk4[2], pk4[3] };
          *(v4s*)&vtw[(((size_t)b * NHEAD + h) * DHE + d) * S_LEN + s] = pk;
        }
      }
    }
}

// ---------------- batched 768x768 weight transpose: z -> (matrix m = z>>2, layer l = z&3) ----
__global__ __launch_bounds__(256)
void qkvo_trans(const float* __restrict__ Wq, const float* __restrict__ Wk,
                const float* __restrict__ Wv, const float* __restrict__ Wo,
                short* __restrict__ wqkvt, short* __restrict__ wot)
{
  __shared__ float t[32][33];
  const int n0 = blockIdx.x * 32, k0 = blockIdx.y * 32;
  const int l = blockIdx.z & 3, m = blockIdx.z >> 2;
  const size_t DD = (size_t)D_MODEL * D_MODEL;
  const size_t QL = (size_t)QKVN * D_MODEL;
  const float* src = (m == 0 ? Wq : m == 1 ? Wk : m == 2 ? Wv : Wo) + (size_t)l * DD;
  short* dst = (m < 3) ? (wqkvt + (size_t)l * QL + (size_t)m * D_MODEL * D_MODEL)
                       : (wot + (size_t)l * DD);
  const float scale = (m == 0) ? 0.125f : 1.0f;
  const int tx = threadIdx.x, ty = threadIdx.y;   // (32,8)
#pragma unroll
  for (int i = 0; i < 4; ++i)
    t[ty + 8*i][tx] = src[(size_t)(k0 + ty + 8*i) * D_MODEL + n0 + tx];
  __syncthreads();
#pragma unroll
  for (int i = 0; i < 4; ++i)
    dst[(size_t)(n0 + ty + 8*i) * D_MODEL + k0 + tx] = f2bf(t[tx][ty + 8*i] * scale);
}

// ---------------- weight transpose f32[K,N] -> bf16[N,K] (Wi / Wf) ----------------
__global__ __launch_bounds__(256)
void transpose_w(const float* __restrict__ in, short* __restrict__ out, int K, int N,
                 size_t in_ls, size_t out_ls, float scale)
{
  __shared__ float t[32][33];
  const int n0 = blockIdx.x * 32, k0 = blockIdx.y * 32;
  const float* src = in + (size_t)blockIdx.z * in_ls;
  short* dst = out + (size_t)blockIdx.z * out_ls;
  const int tx = threadIdx.x, ty = threadIdx.y;   // (32,8)
#pragma unroll
  for (int i = 0; i < 4; ++i)
    t[ty + 8*i][tx] = src[(size_t)(k0 + ty + 8*i) * N + n0 + tx];
  __syncthreads();
#pragma unroll
  for (int i = 0; i < 4; ++i)
    dst[(size_t)(n0 + ty + 8*i) * K + k0 + tx] = f2bf(t[tx][ty + 8*i] * scale);
}

__global__ void prep_bias(const float* __restrict__ bq, const float* __restrict__ bk,
                          const float* __restrict__ bv, float* __restrict__ out)
{
  const int l = blockIdx.x, p = blockIdx.y, c = threadIdx.x;
  const float* s = p == 0 ? bq : (p == 1 ? bk : bv);
  out[(l * 3 + p) * 768 + c] = s[l * 768 + c] * (p == 0 ? 0.125f : 1.0f);
}

// ---------------- LayerNorm, bf16 residual stream (R10-proven precision path) ----------------
template<int MODE, int FINAL>
__global__ __launch_bounds__(256)
void ln_kernel(const void* __restrict__ in0, const void* __restrict__ in1,
               const float* __restrict__ in2,
               const float* __restrict__ gamma, const float* __restrict__ beta,
               float* __restrict__ outf, short* __restrict__ outb)
{
  __shared__ float red[8];
  const int row = blockIdx.x;
  const int tid = threadIdx.x;
  const int wave = tid >> 6, lane = tid & 63;
  float v[3];
#pragma unroll
  for (int i = 0; i < 3; ++i) {
    const int c = tid + i * 256;
    const size_t idx = (size_t)row * D_MODEL + c;
    if (MODE == 0) {
      const int s = row & (S_LEN - 1);
      v[i] = ((const float*)in0)[idx] + ((const float*)in1)[(size_t)(2 + s) * D_MODEL + c] + in2[c];
    } else {
      v[i] = b2f(((const short*)in0)[idx]) + b2f(((const short*)in1)[idx]);
    }
  }
  float sum = v[0] + v[1] + v[2];
#pragma unroll
  for (int m = 1; m < 64; m <<= 1) sum += __shfl_xor(sum, m, 64);
  if (lane == 0) red[wave] = sum;
  __syncthreads();
  const float mean = (red[0] + red[1] + red[2] + red[3]) * (1.0f / 768.0f);
  float sq = 0.f;
#pragma unroll
  for (int i = 0; i < 3; ++i) { float d = v[i] - mean; sq += d * d; }
#pragma unroll
  for (int m = 1; m < 64; m <<= 1) sq += __shfl_xor(sq, m, 64);
  if (lane == 0) red[4 + wave] = sq;
  __syncthreads();
  const float var = (red[4] + red[5] + red[6] + red[7]) * (1.0f / 768.0f);
  const float rstd = 1.0f / sqrtf(var + 1e-12f);
#pragma unroll
  for (int i = 0; i < 3; ++i) {
    const int c = tid + i * 256;
    const size_t idx = (size_t)row * D_MODEL + c;
    const float o = (v[i] - mean) * rstd * gamma[c] + beta[c];
    if (FINAL) outf[idx] = o;
    outb[idx] = f2bf(o);
  }
}

// ---------------- fused attention v5 (R14-proven): V fetch hides under QK^T ----------------
__global__ __launch_bounds__(256, 2)
void att_fused(const short* __restrict__ qkv, const short* __restrict__ vt,
               const int* __restrict__ lengths, short* __restrict__ ctx)
{
  __shared__ __align__(16) short KP[320 * 64];   // K-window; later P [64][640B]
  __shared__ __align__(16) short Vl[64 * 320];   // Vt-window [64][640B]
  const int p = blockIdx.x;
  const int lb = (p & 7) * 192 + (p >> 3);       // XCD-contiguous: same (b,h) per XCD
  const int hq = lb & 1, c = (lb >> 1) & 31, bh = lb >> 6;
  const int b = bh / 12, h = bh - b * 12;
  const int len = lengths[b];
  const int tid = threadIdx.x;
  const int wave = tid >> 6, lane = tid & 63;
  const int g = lane >> 4, l16 = lane & 15;
  const int j0h = c * W1_ + hq * 64 - W1_;       // global j of window index 0

  // ---- stage K window  [10 issues]
  {
    const int row0 = tid >> 3;
    const int o = (tid & 7) * 16;
    const char* kcol = (const char*)qkv + (size_t)b * S_LEN * 4608 + 1536 + h * 128;
#pragma unroll
    for (int i = 0; i < 10; ++i) {
      const int r_ = i * 32 + row0;
      const int op = o ^ ((r_ & 7) << 4);
      int jg = j0h + r_;
      jg = jg < 0 ? 0 : (jg > S_LEN - 1 ? S_LEN - 1 : jg);
      load_lds16((const short*)(kcol + (size_t)jg * 4608 + op),
                 (short*)((char*)KP + i * 4096 + wave * 1024));
    }
  }
  __builtin_amdgcn_sched_barrier(0);
  // ---- Q fragments  [2 loads]
  const int qrow = c * W1_ + hq * 64 + wave * 16 + l16;
  const short* qp = qkv + (size_t)(b * S_LEN + qrow) * QKVN + h * DHE;
  const v8s a0 = *(const v8s*)(qp + g * 8);
  const v8s a1 = *(const v8s*)(qp + 32 + g * 8);
  __builtin_amdgcn_sched_barrier(0);
  // ---- stage Vt window  [10 issues, in flight through QK^T]
  {
    const char* vrow = (const char*)vt + ((size_t)(b * NHEAD + h) * DHE) * (S_LEN * 2);
#pragma unroll
    for (int r = 0; r < 10; ++r) {
      const int off = r * 4096 + tid * 16;
      const int rw = (int)(((unsigned)off * 6554u) >> 22);   // off / 640
      const int o = off - rw * 640;
      int jb = j0h * 2 + (o ^ ((rw & 7) << 4));
      jb = jb < 0 ? 0 : (jb > S_LEN * 2 - 16 ? S_LEN * 2 - 16 : jb);
      load_lds16((const short*)(vrow + (size_t)rw * (S_LEN * 2) + jb),
                 (short*)((char*)Vl + r * 4096 + wave * 1024));
    }
  }
  __builtin_amdgcn_sched_barrier(0);
  asm volatile("s_waitcnt vmcnt(10)" ::: "memory");   // K+Q done; V in flight
  __builtin_amdgcn_sched_barrier(0);
  __builtin_amdgcn_s_barrier();

  // ---- swapped QK^T
  v4f s[20];
  const int kswz = (l16 & 7) << 4;
#pragma unroll
  for (int nt = 0; nt < 20; ++nt) {
    const char* krow = (const char*)KP + (nt * 16 + l16) * 128;
    const v8s k0 = *(const v8s*)(krow + ((g * 16) ^ kswz));
    const v8s k1 = *(const v8s*)(krow + ((64 + g * 16) ^ kswz));
    v4f t = {0.f, 0.f, 0.f, 0.f};
    t = __builtin_amdgcn_mfma_f32_16x16x32_bf16(k0, a0, t, 0, 0, 0);
    t = __builtin_amdgcn_mfma_f32_16x16x32_bf16(k1, a1, t, 0, 0, 0);
    s[nt] = t;
  }

  // ---- mask + softmax
  const int qloc = wave * 16 + l16;
  float m = -3.0e38f;
#pragma unroll
  for (int nt = 0; nt < 20; ++nt)
#pragma unroll
    for (int r = 0; r < 4; ++r) {
      const int j = nt * 16 + g * 4 + r;
      const int jg = j0h + j;
      const bool ok = (j >= qloc) & (j <= qloc + 2 * W1_) & (jg >= 0) & (jg < len);
      const float v = ok ? s[nt][r] : -1e9f;
      s[nt][r] = v;
      m = fmaxf(m, v);
    }
  m = fmaxf(m, __shfl_xor(m, 16, 64));
  m = fmaxf(m, __shfl_xor(m, 32, 64));
  float su = 0.f;
#pragma unroll
  for (int nt = 0; nt < 20; ++nt)
#pragma unroll
    for (int r = 0; r < 4; ++r) {
      const float e = __expf(s[nt][r] - m);
      s[nt][r] = e;
      su += e;
    }
  su += __shfl_xor(su, 16, 64);
  su += __shfl_xor(su, 32, 64);
  const float f = (qrow < len) ? 1.0f / su : 0.0f;

  // ---- drain V, barrier, overwrite K with P
  asm volatile("s_waitcnt vmcnt(0)" ::: "memory");
  __builtin_amdgcn_sched_barrier(0);
  __builtin_amdgcn_s_barrier();
  const int pswz = (qloc & 7) << 4;
  char* prow = (char*)KP + qloc * 640;
#pragma unroll
  for (int nt = 0; nt < 20; ++nt) {
    v4s pk;
#pragma unroll
    for (int r = 0; r < 4; ++r) pk[r] = f2bf(s[nt][r] * f);
    *(v4s*)(prow + ((nt * 32 + g * 8) ^ pswz)) = pk;
  }
  asm volatile("s_waitcnt lgkmcnt(0)" ::: "memory");
  __builtin_amdgcn_sched_barrier(0);

  // ---- PV from LDS
  v4f acc[4] = {};
#pragma unroll
  for (int kc = 0; kc < 10; ++kc) {
    const v8s fa = *(const v8s*)(prow + ((kc * 64 + g * 16) ^ pswz));
#pragma unroll
    for (int dt = 0; dt < 4; ++dt) {
      const int vr = dt * 16 + l16;
      const v8s fb = *(const v8s*)((char*)Vl + vr * 640 + ((kc * 64 + g * 16) ^ ((vr & 7) << 4)));
      acc[dt] = __builtin_amdgcn_mfma_f32_16x16x32_bf16(fa, fb, acc[dt], 0, 0, 0);
    }
  }
  const int srow0 = c * W1_ + hq * 64 + wave * 16;
#pragma unroll
  for (int dt = 0; dt < 4; ++dt)
#pragma unroll
    for (int r = 0; r < 4; ++r)
      ctx[(size_t)(b * S_LEN + srow0 + g * 4 + r) * D_MODEL + h * DHE + dt * 16 + l16] = f2bf(acc[dt][r]);
}

extern "C" void kernel_launch(void* const* d_in, const int* in_sizes, int n_in,
                              void* d_out, int out_size, void* d_ws, size_t ws_size,
                              hipStream_t stream) {
  (void)in_sizes; (void)n_in; (void)out_size; (void)ws_size;
  const float* inputs  = (const float*)d_in[0];
  const int*   lengths = (const int*)d_in[1];
  const float* pos_emb = (const float*)d_in[2];
  const float* tok_emb = (const float*)d_in[3];
  const float* ln_emb_g = (const float*)d_in[4];
  const float* ln_emb_b = (const float*)d_in[5];
  const float* Wq = (const float*)d_in[6];
  const float* bq = (const float*)d_in[7];
  const float* Wk = (const float*)d_in[8];
  const float* bk = (const float*)d_in[9];
  const float* Wv = (const float*)d_in[10];
  const float* bv = (const float*)d_in[11];
  const float* Wo = (const float*)d_in[12];
  const float* bo = (const float*)d_in[13];
  const float* ln1_g = (const float*)d_in[14];
  const float* ln1_b = (const float*)d_in[15];
  const float* Wi = (const float*)d_in[16];
  const float* bi = (const float*)d_in[17];
  const float* Wf = (const float*)d_in[18];
  const float* bf2 = (const float*)d_in[19];
  const float* ln2_g = (const float*)d_in[20];
  const float* ln2_b = (const float*)d_in[21];

  const size_t MTOK = (size_t)2 * S_LEN;     // 8192
  const size_t DD  = (size_t)D_MODEL * D_MODEL;
  const size_t DDF = (size_t)D_MODEL * DFF_;

  char* ws = (char*)d_ws;
  size_t off = 0;
  auto alloc = [&](size_t bytes) { void* p = ws + off; off += (bytes + 255) & ~(size_t)255; return p; };

  short* xb    = (short*)alloc(MTOK * D_MODEL * 2);
  short* qkv   = (short*)alloc(MTOK * QKVN * 2);
  short* vtb   = (short*)alloc(MTOK * D_MODEL * 2);
  short* yb    = (short*)alloc(MTOK * D_MODEL * 2);
  short* ctxb  = (short*)alloc(MTOK * D_MODEL * 2);
  short* hb    = (short*)alloc(MTOK * DFF_ * 2);
  short* wqkvt = (short*)alloc((size_t)NL * QKVN * D_MODEL * 2);
  short* wot   = (short*)alloc((size_t)NL * DD * 2);
  short* wit   = (short*)alloc((size_t)NL * DDF * 2);
  short* wft   = (short*)alloc((size_t)NL * DDF * 2);
  float* bqkv  = (float*)alloc((size_t)NL * QKVN * 4);
  float* x = (float*)d_out;

  const dim3 tb(32, 8);
  const size_t QL = (size_t)QKVN * D_MODEL;
  qkvo_trans<<<dim3(24, 24, 16), tb, 0, stream>>>(Wq, Wk, Wv, Wo, wqkvt, wot);
  transpose_w<<<dim3(96, 24, NL), tb, 0, stream>>>(Wi, wit, D_MODEL, DFF_, DDF, DDF, 1.0f);
  transpose_w<<<dim3(24, 96, NL), tb, 0, stream>>>(Wf, wft, DFF_, D_MODEL, DDF, DDF, 1.0f);
  prep_bias<<<dim3(NL, 3), 768, 0, stream>>>(bq, bk, bv, bqkv);

  ln_kernel<0, 0><<<MTOK, 256, 0, stream>>>(inputs, pos_emb, tok_emb, ln_emb_g, ln_emb_b, x, xb);

  for (int l = 0; l < NL; ++l) {
    gemm128<128, 0, 1><<<dim3(18, 64), 512, 0, stream>>>(xb, wqkvt + (size_t)l * QL, bqkv + (size_t)l * QKVN,
                                                         qkv, vtb, (int)MTOK, QKVN, D_MODEL);
    att_fused<<<dim3(1536), 256, 0, stream>>>(qkv, vtb, lengths, ctxb);
    gemm128<64, 0, 0><<<dim3(12, 64), 512, 0, stream>>>(ctxb, wot + (size_t)l * DD, bo + l * D_MODEL,
                                                        yb, nullptr, (int)MTOK, D_MODEL, D_MODEL);
    ln_kernel<1, 0><<<MTOK, 256, 0, stream>>>(xb, yb, nullptr, ln1_g + l * D_MODEL, ln1_b + l * D_MODEL, x, xb);
    gemm128<128, 2, 0><<<dim3(24, 64), 512, 0, stream>>>(xb, wit + (size_t)l * DDF, bi + l * DFF_,
                                                         hb, nullptr, (int)MTOK, DFF_, D_MODEL);
    gemm128<64, 0, 0><<<dim3(12, 64), 512, 0, stream>>>(hb, wft + (size_t)l * DDF, bf2 + l * D_MODEL,
                                                        yb, nullptr, (int)MTOK, D_MODEL, DFF_);
    if (l < NL - 1)
      ln_kernel<1, 0><<<MTOK, 256, 0, stream>>>(xb, yb, nullptr, ln2_g + l * D_MODEL, ln2_b + l * D_MODEL, x, xb);
    else
      ln_kernel<1, 1><<<MTOK, 256, 0, stream>>>(xb, yb, nullptr, ln2_g + l * D_MODEL, ln2_b + l * D_MODEL, x, xb);
  }
}